// Round 1
// baseline (6429.822 us; speedup 1.0000x reference)
//
#include <hip/hip_runtime.h>
#include <math.h>

#define N_    128
#define CIN   64
#define COUT  64
#define T_    256
#define V_    17
#define K_    3
#define NCH   (N_*COUT)        // 8192
#define TV    (T_*V_)          // 4352
#define AF_VSTRIDE 20
#define AF_KC (V_*AF_VSTRIDE)  // 340

// workspace layout (float offsets)
#define OFF_XBAR 0
#define SZ_XBAR  (NCH*V_)                  // 139264
#define OFF_WBAR (OFF_XBAR+SZ_XBAR)
#define SZ_WBAR  (24*64)
#define OFF_BBAR (OFF_WBAR+SZ_WBAR)
#define SZ_BBAR  32
#define OFF_POOL (OFF_BBAR+SZ_BBAR)
#define SZ_POOL  NCH
#define OFF_SIG  (OFF_POOL+SZ_POOL)
#define SZ_SIG   NCH
#define OFF_AFIN (OFF_SIG+SZ_SIG)
#define SZ_AFIN  (N_*K_*COUT*AF_KC)        // 8,355,840 floats (~33.4 MB)

// ---------------- K1: xbar[n,c,v] = mean_t x0[n,c,t,v] ----------------
// 272 = 16*17 threads: thread tid owns v = tid%17 (since 272 % 17 == 0)
__global__ __launch_bounds__(272) void k1_xbar(const float* __restrict__ x0,
                                               float* __restrict__ xbar) {
    int nc = blockIdx.x;
    __shared__ float s[272];
    const float* p = x0 + (size_t)nc * TV;
    int tid = threadIdx.x;
    float acc = 0.f;
#pragma unroll
    for (int j = 0; j < 16; ++j) acc += p[j*272 + tid];
    s[tid] = acc;
    __syncthreads();
    if (tid < V_) {
        float t = 0.f;
#pragma unroll
        for (int ts = 0; ts < 16; ++ts) t += s[ts*V_ + tid];
        xbar[nc*V_ + tid] = t * (1.f / (float)T_);
    }
}

// ---------------- K2a: group-averaged conv weights --------------------
// wbar[o4][c] = mean_{c8} conv_w[k*64 + j*16 + q*8 + c8][c], o4 = k*8+j*2+q
__global__ void k2a_wbar(const float* __restrict__ cw, const float* __restrict__ cb,
                         float* __restrict__ wbar, float* __restrict__ bbar) {
    int idx = threadIdx.x + blockIdx.x * 256;
    if (idx < 24*64) {
        int o4 = idx >> 6, c = idx & 63;
        int k = o4 >> 3, jq = o4 & 7;
        int j = jq >> 1, q = jq & 1;
        int ob = k*64 + j*16 + q*8;
        float s = 0.f;
#pragma unroll
        for (int c8 = 0; c8 < 8; ++c8) s += cw[(ob + c8)*64 + c];
        wbar[idx] = s * 0.125f;
    }
    if (idx < 24) {
        int k = idx >> 3, jq = idx & 7;
        int j = jq >> 1, q = jq & 1;
        int ob = k*64 + j*16 + q*8;
        float s = 0.f;
#pragma unroll
        for (int c8 = 0; c8 < 8; ++c8) s += cb[ob + c8];
        bbar[idx] = s * 0.125f;
    }
}

// ---------------- K2: attention math -> A_final (per n) ---------------
__global__ __launch_bounds__(256) void k2_attn(
    const float* __restrict__ xbar, const float* __restrict__ wbar,
    const float* __restrict__ bbar,
    const float* __restrict__ spa_w, const float* __restrict__ spa_b,
    const float* __restrict__ mix_w, const float* __restrict__ mix_b,
    const float* __restrict__ A_GEME, const float* __restrict__ A_SE,
    float* __restrict__ afin) {
    int n = blockIdx.x;
    int tid = threadIdx.x;
    __shared__ float xb[CIN*V_];     // [c][v]
    __shared__ float wb[24*64];
    __shared__ float bb[24];
    __shared__ float sw_[289], sb_[17], mw_[289], mb_[17];
    __shared__ float QK[24*V_];      // [o4][v]
    __shared__ float F[4*12*V_];     // 0=QT,1=KT,2=Kc,3=Qc : [f][u][v], u=k*4+j
    __shared__ float S_[12*V_*V_];
    __shared__ float X_[9*V_*V_];
    __shared__ float AC[12*V_*V_];

    for (int i = tid; i < CIN*V_; i += 256) xb[i] = xbar[n*CIN*V_ + i];
    for (int i = tid; i < 24*64; i += 256) wb[i] = wbar[i];
    if (tid < 24) bb[tid] = bbar[tid];
    for (int i = tid; i < 289; i += 256) { sw_[i] = spa_w[i]; mw_[i] = mix_w[i]; }
    if (tid < 17) { sb_[tid] = spa_b[tid]; mb_[tid] = mix_b[tid]; }
    __syncthreads();

    // QK[o4][v] = bbar[o4] + sum_c xbar[c][v]*wbar[o4][c]
    for (int i = tid; i < 24*V_; i += 256) {
        int o4 = i / V_, v = i % V_;
        float s = bb[o4];
        for (int c = 0; c < CIN; ++c) s += xb[c*V_ + v] * wb[o4*64 + c];
        QK[i] = s;
    }
    __syncthreads();

    // QT/KT/Kc/Qc = relu(lin(Qo/Ko, W, b))
    for (int i = tid; i < 4*12*V_; i += 256) {
        int f = i / (12*V_); int r = i % (12*V_);
        int u = r / V_; int vp = r % V_;
        int k = u >> 2, j = u & 3;
        int q = (f == 1 || f == 2) ? 1 : 0;   // KT, Kc use Ko
        const float* src  = &QK[(k*8 + j*2 + q) * V_];
        const float* wmat = (f <= 1) ? sw_ : mw_;
        const float* bvec = (f <= 1) ? sb_ : mb_;
        float s = bvec[vp];
#pragma unroll
        for (int v = 0; v < V_; ++v) s += src[v] * wmat[vp*V_ + v];
        F[i] = fmaxf(s, 0.f);
    }
    __syncthreads();

    // S rows (12 units) and X rows (9 units): softmax_w(a_v * b_w)
    for (int r = tid; r < (12+9)*V_; r += 256) {
        float a; const float* brow; float* orow;
        if (r < 12*V_) {
            int u = r / V_, v = r % V_;
            a = F[0*12*V_ + u*V_ + v];
            brow = &F[1*12*V_ + u*V_];
            orow = &S_[u*V_*V_ + v*V_];
        } else {
            int rx = r - 12*V_;
            int xu = rx / V_, v = rx % V_;
            int k = xu / 3, j = xu % 3;
            a = F[2*12*V_ + (k*4 + j)*V_ + v];
            brow = &F[3*12*V_ + (k*4 + j + 1)*V_];
            orow = &X_[xu*V_*V_ + v*V_];
        }
        float vals[V_];
        float mx = -1e30f;
#pragma unroll
        for (int w = 0; w < V_; ++w) { vals[w] = a * brow[w]; mx = fmaxf(mx, vals[w]); }
        float sum = 0.f;
#pragma unroll
        for (int w = 0; w < V_; ++w) { vals[w] = expf(vals[w] - mx); sum += vals[w]; }
        float inv = 1.f / sum;
#pragma unroll
        for (int w = 0; w < V_; ++w) orow[w] = vals[w] * inv;
    }
    __syncthreads();

    // atten chunks: m1..m4 per k
    for (int i = tid; i < 12*V_*V_; i += 256) {
        int u = i / (V_*V_); int vw = i % (V_*V_);
        int k = u >> 2, jj = u & 3;
        int xb3 = k*3;
        float s = 0.5f * S_[i];
        if (jj == 0)      s += 0.25f *  X_[(xb3+0)*V_*V_ + vw];
        else if (jj == 1) s += 0.25f * (X_[(xb3+0)*V_*V_ + vw] + X_[(xb3+1)*V_*V_ + vw]);
        else if (jj == 2) s += 0.25f * (X_[(xb3+1)*V_*V_ + vw] + X_[(xb3+2)*V_*V_ + vw]);
        else              s += 0.25f *  X_[(xb3+2)*V_*V_ + vw];
        AC[i] = s;
    }
    __syncthreads();

    // A_final[n,k,c,v,w] = 0.5*AC[k, c>>4, v,w] + (A_SE+A_GEME)[k, c&7, v,w]
    float* out = afin + (size_t)n * (K_*COUT*AF_KC);
    for (int i = tid; i < K_*COUT*AF_KC; i += 256) {
        int k  = i / (COUT*AF_KC);
        int r  = i % (COUT*AF_KC);
        int c  = r / AF_KC;
        int vw = r % AF_KC;
        int v = vw / AF_VSTRIDE, w = vw % AF_VSTRIDE;
        float val = 0.f;
        if (w < V_) {
            int g = k*8 + (c & 7);
            val = 0.5f * AC[(k*4 + (c >> 4))*V_*V_ + v*V_ + w]
                + A_SE[g*V_*V_ + v*V_ + w] + A_GEME[g*V_*V_ + v*V_ + w];
        }
        out[i] = val;
    }
}

// ---------------- K3: conv + apply A_final + partial pool -------------
template<int KIDX>
__device__ __forceinline__ void apply_k(const float* __restrict__ afin, int n, int c,
                                        const float (&mk)[V_], float (&yv)[V_]) {
    const float* af_kc = afin + ((size_t)((n*3 + KIDX)*COUT + c)) * AF_KC;
#pragma unroll
    for (int v = 0; v < V_; ++v) {
        float av = mk[v];
        const float* afr = af_kc + v*AF_VSTRIDE;
        float4 f0 = *(const float4*)(afr);
        float4 f1 = *(const float4*)(afr + 4);
        float4 f2 = *(const float4*)(afr + 8);
        float4 f3 = *(const float4*)(afr + 12);
        float f16 = afr[16];
        yv[0]  += av*f0.x; yv[1]  += av*f0.y; yv[2]  += av*f0.z; yv[3]  += av*f0.w;
        yv[4]  += av*f1.x; yv[5]  += av*f1.y; yv[6]  += av*f1.z; yv[7]  += av*f1.w;
        yv[8]  += av*f2.x; yv[9]  += av*f2.y; yv[10] += av*f2.z; yv[11] += av*f2.w;
        yv[12] += av*f3.x; yv[13] += av*f3.y; yv[14] += av*f3.z; yv[15] += av*f3.w;
        yv[16] += av*f16;
    }
}

__global__ __launch_bounds__(256) void k3_main(
    const float* __restrict__ x0, const float* __restrict__ cw,
    const float* __restrict__ cb, const float* __restrict__ afin,
    float* __restrict__ y, float* __restrict__ pooled) {
    int n  = blockIdx.y;
    int t0 = blockIdx.x * 8;
    int tid = threadIdx.x;
    __shared__ float xs[CIN*8*AF_VSTRIDE];   // [ci][t][20], 40.96 KB
    __shared__ float pool_s[COUT];

    const float* xsrc = x0 + (size_t)n * (CIN*TV);
    for (int i = tid; i < CIN*8*V_; i += 256) {
        int ci = i / (8*V_); int r = i % (8*V_);
        int t = r / V_; int v = r % V_;
        xs[ci*160 + t*20 + v] = xsrc[ci*TV + (t0 + t)*V_ + v];
    }
    if (tid < COUT) pool_s[tid] = 0.f;
    __syncthreads();

#pragma unroll
    for (int it = 0; it < 2; ++it) {
        int p = tid + 256*it;
        int c = p >> 3, t = p & 7;

        float m0[V_], m1[V_], m2[V_];
        float b0 = cb[c], b1 = cb[64 + c], b2 = cb[128 + c];
#pragma unroll
        for (int v = 0; v < V_; ++v) { m0[v] = b0; m1[v] = b1; m2[v] = b2; }

        const float* w0p = cw + (size_t)c * 64;
        const float* w1p = cw + (size_t)(64 + c) * 64;
        const float* w2p = cw + (size_t)(128 + c) * 64;

#pragma unroll
        for (int ci4 = 0; ci4 < 16; ++ci4) {
            float4 wa = *(const float4*)(w0p + ci4*4);
            float4 wbv = *(const float4*)(w1p + ci4*4);
            float4 wc = *(const float4*)(w2p + ci4*4);
            float wax[4] = {wa.x, wa.y, wa.z, wa.w};
            float wbx[4] = {wbv.x, wbv.y, wbv.z, wbv.w};
            float wcx[4] = {wc.x, wc.y, wc.z, wc.w};
#pragma unroll
            for (int u = 0; u < 4; ++u) {
                int ci = ci4*4 + u;
                const float* xr = &xs[ci*160 + t*20];
                float4 xv0 = *(const float4*)(xr);
                float4 xv1 = *(const float4*)(xr + 4);
                float4 xv2 = *(const float4*)(xr + 8);
                float4 xv3 = *(const float4*)(xr + 12);
                float x16 = xr[16];
                float xa[V_];
                xa[0]=xv0.x;  xa[1]=xv0.y;  xa[2]=xv0.z;  xa[3]=xv0.w;
                xa[4]=xv1.x;  xa[5]=xv1.y;  xa[6]=xv1.z;  xa[7]=xv1.w;
                xa[8]=xv2.x;  xa[9]=xv2.y;  xa[10]=xv2.z; xa[11]=xv2.w;
                xa[12]=xv3.x; xa[13]=xv3.y; xa[14]=xv3.z; xa[15]=xv3.w;
                xa[16]=x16;
                float wA = wax[u], wB = wbx[u], wC = wcx[u];
#pragma unroll
                for (int v = 0; v < V_; ++v) {
                    m0[v] += wA * xa[v];
                    m1[v] += wB * xa[v];
                    m2[v] += wC * xa[v];
                }
            }
        }

        float yv[V_];
#pragma unroll
        for (int w = 0; w < V_; ++w) yv[w] = 0.f;
        apply_k<0>(afin, n, c, m0, yv);
        apply_k<1>(afin, n, c, m1, yv);
        apply_k<2>(afin, n, c, m2, yv);

        float sw = 0.f;
#pragma unroll
        for (int w = 0; w < V_; ++w) sw += yv[w];
        atomicAdd(&pool_s[c], sw);

        float* yout = y + ((size_t)(n*COUT + c)*T_ + (t0 + t)) * V_;
#pragma unroll
        for (int w = 0; w < V_; ++w) yout[w] = yv[w];
    }
    __syncthreads();
    if (tid < COUT) atomicAdd(&pooled[n*COUT + tid], pool_s[tid]);
}

// ---------------- K4: channel conv1d + sigmoid ------------------------
__global__ void k4_sig(const float* __restrict__ pooled, const float* __restrict__ cha_w,
                       float* __restrict__ sig) {
    int idx = threadIdx.x + blockIdx.x * 256;
    if (idx >= NCH) return;
    int c = idx & 63;
    const float inv = 1.f / (float)TV;
    float pm = pooled[idx] * inv;
    float pl = (c > 0)  ? pooled[idx - 1] * inv : 0.f;
    float pr = (c < 63) ? pooled[idx + 1] * inv : 0.f;
    float cr = cha_w[0]*pl + cha_w[1]*pm + cha_w[2]*pr;
    sig[idx] = 1.f / (1.f + expf(-cr));
}

// ---------------- K5: gate + BN + residual + relu (in place) ----------
__global__ __launch_bounds__(256) void k5_final(
    const float* __restrict__ x0, const float* __restrict__ sig,
    const float* __restrict__ gamma, const float* __restrict__ beta,
    float* __restrict__ y) {
    const float inv_sqrt = rsqrtf(1.f + 1e-5f);
    long long i = (long long)blockIdx.x * 256 + threadIdx.x;
    const long long total = (long long)N_*COUT*TV/4;  // 8,912,896
    const long long stride = (long long)gridDim.x * 256;
    for (; i < total; i += stride) {
        int nc = (int)(i / (TV/4));    // 1088 float4 per (n,c)
        int c = nc & 63;
        float a = (1.f + sig[nc]) * gamma[c] * inv_sqrt;
        float b = beta[c];
        float4 yv = ((const float4*)y)[i];
        float4 xv = ((const float4*)x0)[i];
        float4 o;
        o.x = fmaxf(yv.x*a + b + xv.x, 0.f);
        o.y = fmaxf(yv.y*a + b + xv.y, 0.f);
        o.z = fmaxf(yv.z*a + b + xv.z, 0.f);
        o.w = fmaxf(yv.w*a + b + xv.w, 0.f);
        ((float4*)y)[i] = o;
    }
}

extern "C" void kernel_launch(void* const* d_in, const int* in_sizes, int n_in,
                              void* d_out, int out_size, void* d_ws, size_t ws_size,
                              hipStream_t stream) {
    const float* x0     = (const float*)d_in[0];
    const float* conv_w = (const float*)d_in[1];
    const float* conv_b = (const float*)d_in[2];
    const float* spa_w  = (const float*)d_in[3];
    const float* spa_b  = (const float*)d_in[4];
    const float* mix_w  = (const float*)d_in[5];
    const float* mix_b  = (const float*)d_in[6];
    const float* A_GEME = (const float*)d_in[7];
    const float* A_SE   = (const float*)d_in[8];
    const float* cha_w  = (const float*)d_in[9];
    const float* gamma  = (const float*)d_in[10];
    const float* beta   = (const float*)d_in[11];

    float* ws    = (float*)d_ws;
    float* xbar  = ws + OFF_XBAR;
    float* wbar  = ws + OFF_WBAR;
    float* bbar  = ws + OFF_BBAR;
    float* pooled= ws + OFF_POOL;
    float* sig   = ws + OFF_SIG;
    float* afin  = ws + OFF_AFIN;
    float* y     = (float*)d_out;

    hipMemsetAsync(pooled, 0, NCH*sizeof(float), stream);
    k1_xbar<<<NCH, 272, 0, stream>>>(x0, xbar);
    k2a_wbar<<<6, 256, 0, stream>>>(conv_w, conv_b, wbar, bbar);
    k2_attn<<<N_, 256, 0, stream>>>(xbar, wbar, bbar, spa_w, spa_b,
                                    mix_w, mix_b, A_GEME, A_SE, afin);
    k3_main<<<dim3(32, 128), 256, 0, stream>>>(x0, conv_w, conv_b, afin, y, pooled);
    k4_sig<<<32, 256, 0, stream>>>(pooled, cha_w, sig);
    k5_final<<<2048, 256, 0, stream>>>(x0, sig, gamma, beta, y);
}

// Round 2
// 495.044 us; speedup vs baseline: 12.9884x; 12.9884x over previous
//
#include <hip/hip_runtime.h>
#include <math.h>

#define N_    128
#define CIN   64
#define COUT  64
#define T_    256
#define V_    17
#define K_    3
#define NCH   (N_*COUT)        // 8192
#define TV    (T_*V_)          // 4352

// workspace layout (float offsets)
#define OFF_XBAR 0
#define SZ_XBAR  (NCH*V_)                  // 139264
#define OFF_WBAR (OFF_XBAR+SZ_XBAR)
#define SZ_WBAR  (24*64)
#define OFF_BBAR (OFF_WBAR+SZ_WBAR)
#define SZ_BBAR  32
#define OFF_POOL (OFF_BBAR+SZ_BBAR)
#define SZ_POOL  NCH
#define OFF_SIG  (OFF_POOL+SZ_POOL)
#define SZ_SIG   NCH
#define OFF_AC   (OFF_SIG+SZ_SIG)
#define SZ_AC    (N_*12*289)               // 443904 floats (0.5*atten_chunks)
#define OFF_NA   (OFF_AC+SZ_AC)
#define SZ_NA    (K_*8*289)                // 6936 (A_SE + A_GEME)

// ---------------- K1: xbar[n,c,v] = mean_t x0[n,c,t,v] ----------------
__global__ __launch_bounds__(272) void k1_xbar(const float* __restrict__ x0,
                                               float* __restrict__ xbar) {
    int nc = blockIdx.x;
    __shared__ float s[272];
    const float* p = x0 + (size_t)nc * TV;
    int tid = threadIdx.x;
    float acc = 0.f;
#pragma unroll
    for (int j = 0; j < 16; ++j) acc += p[j*272 + tid];
    s[tid] = acc;
    __syncthreads();
    if (tid < V_) {
        float t = 0.f;
#pragma unroll
        for (int ts = 0; ts < 16; ++ts) t += s[ts*V_ + tid];
        xbar[nc*V_ + tid] = t * (1.f / (float)T_);
    }
}

// ---------------- K2a: group-averaged conv weights + NA sum -----------
__global__ void k2a_wbar(const float* __restrict__ cw, const float* __restrict__ cb,
                         const float* __restrict__ A_SE, const float* __restrict__ A_GEME,
                         float* __restrict__ wbar, float* __restrict__ bbar,
                         float* __restrict__ na) {
    int idx = threadIdx.x + blockIdx.x * 256;
    if (idx < 24*64) {
        int o4 = idx >> 6, c = idx & 63;
        int k = o4 >> 3, jq = o4 & 7;
        int j = jq >> 1, q = jq & 1;
        int ob = k*64 + j*16 + q*8;
        float s = 0.f;
#pragma unroll
        for (int c8 = 0; c8 < 8; ++c8) s += cw[(ob + c8)*64 + c];
        wbar[idx] = s * 0.125f;
    }
    if (idx < 24) {
        int k = idx >> 3, jq = idx & 7;
        int j = jq >> 1, q = jq & 1;
        int ob = k*64 + j*16 + q*8;
        float s = 0.f;
#pragma unroll
        for (int c8 = 0; c8 < 8; ++c8) s += cb[ob + c8];
        bbar[idx] = s * 0.125f;
    }
    if (idx < K_*8*289) {
        na[idx] = A_SE[idx] + A_GEME[idx];
    }
}

// ---------------- K2: attention math -> 0.5*atten_chunks (per n) ------
__global__ __launch_bounds__(256) void k2_attn(
    const float* __restrict__ xbar, const float* __restrict__ wbar,
    const float* __restrict__ bbar,
    const float* __restrict__ spa_w, const float* __restrict__ spa_b,
    const float* __restrict__ mix_w, const float* __restrict__ mix_b,
    float* __restrict__ ac05) {
    int n = blockIdx.x;
    int tid = threadIdx.x;
    __shared__ float xb[CIN*V_];     // [c][v]
    __shared__ float wb[24*64];
    __shared__ float bb[24];
    __shared__ float sw_[289], sb_[17], mw_[289], mb_[17];
    __shared__ float QK[24*V_];      // [o4][v]
    __shared__ float F[4*12*V_];     // 0=QT,1=KT,2=Kc,3=Qc : [f][u][v], u=k*4+j
    __shared__ float S_[12*V_*V_];
    __shared__ float X_[9*V_*V_];

    for (int i = tid; i < CIN*V_; i += 256) xb[i] = xbar[n*CIN*V_ + i];
    for (int i = tid; i < 24*64; i += 256) wb[i] = wbar[i];
    if (tid < 24) bb[tid] = bbar[tid];
    for (int i = tid; i < 289; i += 256) { sw_[i] = spa_w[i]; mw_[i] = mix_w[i]; }
    if (tid < 17) { sb_[tid] = spa_b[tid]; mb_[tid] = mix_b[tid]; }
    __syncthreads();

    // QK[o4][v] = bbar[o4] + sum_c xbar[c][v]*wbar[o4][c]
    for (int i = tid; i < 24*V_; i += 256) {
        int o4 = i / V_, v = i % V_;
        float s = bb[o4];
        for (int c = 0; c < CIN; ++c) s += xb[c*V_ + v] * wb[o4*64 + c];
        QK[i] = s;
    }
    __syncthreads();

    // QT/KT/Kc/Qc = relu(lin(Qo/Ko, W, b))
    for (int i = tid; i < 4*12*V_; i += 256) {
        int f = i / (12*V_); int r = i % (12*V_);
        int u = r / V_; int vp = r % V_;
        int k = u >> 2, j = u & 3;
        int q = (f == 1 || f == 2) ? 1 : 0;   // KT, Kc use Ko
        const float* src  = &QK[(k*8 + j*2 + q) * V_];
        const float* wmat = (f <= 1) ? sw_ : mw_;
        const float* bvec = (f <= 1) ? sb_ : mb_;
        float s = bvec[vp];
#pragma unroll
        for (int v = 0; v < V_; ++v) s += src[v] * wmat[vp*V_ + v];
        F[i] = fmaxf(s, 0.f);
    }
    __syncthreads();

    // S rows (12 units) and X rows (9 units): softmax_w(a_v * b_w)
    for (int r = tid; r < (12+9)*V_; r += 256) {
        float a; const float* brow; float* orow;
        if (r < 12*V_) {
            int u = r / V_, v = r % V_;
            a = F[0*12*V_ + u*V_ + v];
            brow = &F[1*12*V_ + u*V_];
            orow = &S_[u*V_*V_ + v*V_];
        } else {
            int rx = r - 12*V_;
            int xu = rx / V_, v = rx % V_;
            int k = xu / 3, j = xu % 3;
            a = F[2*12*V_ + (k*4 + j)*V_ + v];
            brow = &F[3*12*V_ + (k*4 + j + 1)*V_];
            orow = &X_[xu*V_*V_ + v*V_];
        }
        float vals[V_];
        float mx = -1e30f;
#pragma unroll
        for (int w = 0; w < V_; ++w) { vals[w] = a * brow[w]; mx = fmaxf(mx, vals[w]); }
        float sum = 0.f;
#pragma unroll
        for (int w = 0; w < V_; ++w) { vals[w] = expf(vals[w] - mx); sum += vals[w]; }
        float inv = 1.f / sum;
#pragma unroll
        for (int w = 0; w < V_; ++w) orow[w] = vals[w] * inv;
    }
    __syncthreads();

    // ac05 = 0.5 * atten_chunks  (per k: m1..m4), scaled by 0.5 again:
    // A_final = atten*0.5 + norm_A ; we store 0.5*(S/2 + X/4 terms)
    float* out = ac05 + (size_t)n * (12*289);
    for (int i = tid; i < 12*V_*V_; i += 256) {
        int u = i / (V_*V_); int vw = i % (V_*V_);
        int k = u >> 2, jj = u & 3;
        int xb3 = k*3;
        float s = 0.5f * S_[i];
        if (jj == 0)      s += 0.25f *  X_[(xb3+0)*V_*V_ + vw];
        else if (jj == 1) s += 0.25f * (X_[(xb3+0)*V_*V_ + vw] + X_[(xb3+1)*V_*V_ + vw]);
        else if (jj == 2) s += 0.25f * (X_[(xb3+1)*V_*V_ + vw] + X_[(xb3+2)*V_*V_ + vw]);
        else              s += 0.25f *  X_[(xb3+2)*V_*V_ + vw];
        out[i] = 0.5f * s;
    }
}

// ---------------- K3: conv + apply (LDS AC/NA) + pool + coalesced y ---
// block = (tt, n); TT=4 t-steps; 256 threads; thread -> (c = tid>>2, t = tid&3)
__global__ __launch_bounds__(256) void k3_main(
    const float* __restrict__ x0, const float* __restrict__ cw,
    const float* __restrict__ cb, const float* __restrict__ ac05,
    const float* __restrict__ na, float* __restrict__ y,
    float* __restrict__ pooled) {
    int n  = blockIdx.y;
    int t0 = blockIdx.x * 4;
    int tid = threadIdx.x;
    __shared__ float xs[CIN*4*20];        // [ci][t][20]  20.48 KB (reused as ys)
    __shared__ float ac_s[12*V_*20];      // [k*4+j][v][20] 16.32 KB
    __shared__ float na_s[24*V_*20];      // [k*8+g][v][20] 32.64 KB
    __shared__ float pool_s[COUT];

    // stage x0 tile: x0[n, ci, t0..t0+3, 0..16]
    const float* xsrc = x0 + (size_t)n * (CIN*TV) + (size_t)t0 * V_;
    for (int i = tid; i < CIN*68; i += 256) {
        int ci = i / 68, r = i % 68;
        xs[ci*80 + (r/17)*20 + (r%17)] = xsrc[(size_t)ci*TV + r];
    }
    // stage 0.5*atten (per n) and NA (shared) into padded LDS
    const float* acn = ac05 + (size_t)n * (12*289);
    for (int i = tid; i < 12*289; i += 256) {
        int row = i / 17, w = i % 17;
        ac_s[row*20 + w] = acn[i];
    }
    for (int i = tid; i < 24*289; i += 256) {
        int row = i / 17, w = i % 17;
        na_s[row*20 + w] = na[i];
    }
    if (tid < COUT) pool_s[tid] = 0.f;
    __syncthreads();

    int c = tid >> 2, t = tid & 3;

    // ---- conv: m[k][v] in registers ----
    float m0[V_], m1[V_], m2[V_];
    float b0 = cb[c], b1 = cb[64 + c], b2 = cb[128 + c];
#pragma unroll
    for (int v = 0; v < V_; ++v) { m0[v] = b0; m1[v] = b1; m2[v] = b2; }

    const float* w0p = cw + (size_t)c * 64;
    const float* w1p = cw + (size_t)(64 + c) * 64;
    const float* w2p = cw + (size_t)(128 + c) * 64;

#pragma unroll
    for (int ci4 = 0; ci4 < 16; ++ci4) {
        float4 wa = *(const float4*)(w0p + ci4*4);
        float4 wbv = *(const float4*)(w1p + ci4*4);
        float4 wc = *(const float4*)(w2p + ci4*4);
        float wax[4] = {wa.x, wa.y, wa.z, wa.w};
        float wbx[4] = {wbv.x, wbv.y, wbv.z, wbv.w};
        float wcx[4] = {wc.x, wc.y, wc.z, wc.w};
#pragma unroll
        for (int u = 0; u < 4; ++u) {
            int ci = ci4*4 + u;
            const float* xr = &xs[ci*80 + t*20];
            float4 xv0 = *(const float4*)(xr);
            float4 xv1 = *(const float4*)(xr + 4);
            float4 xv2 = *(const float4*)(xr + 8);
            float4 xv3 = *(const float4*)(xr + 12);
            float x16 = xr[16];
            float xa[V_];
            xa[0]=xv0.x;  xa[1]=xv0.y;  xa[2]=xv0.z;  xa[3]=xv0.w;
            xa[4]=xv1.x;  xa[5]=xv1.y;  xa[6]=xv1.z;  xa[7]=xv1.w;
            xa[8]=xv2.x;  xa[9]=xv2.y;  xa[10]=xv2.z; xa[11]=xv2.w;
            xa[12]=xv3.x; xa[13]=xv3.y; xa[14]=xv3.z; xa[15]=xv3.w;
            xa[16]=x16;
            float wA = wax[u], wB = wbx[u], wC = wcx[u];
#pragma unroll
            for (int v = 0; v < V_; ++v) {
                m0[v] += wA * xa[v];
                m1[v] += wB * xa[v];
                m2[v] += wC * xa[v];
            }
        }
    }

    // ---- apply: y[w] = sum_{k,v} m[k][v] * (ac_s[k][c>>4][v][w] + na_s[k][c&7][v][w])
    float yv[V_];
#pragma unroll
    for (int w = 0; w < V_; ++w) yv[w] = 0.f;
    int jb = c >> 4, g = c & 7;

#pragma unroll
    for (int k = 0; k < 3; ++k) {
        const float* mk = (k == 0) ? m0 : (k == 1) ? m1 : m2;
        const float* acr = &ac_s[(k*4 + jb) * (V_*20)];
        const float* nar = &na_s[(k*8 + g)  * (V_*20)];
#pragma unroll
        for (int v = 0; v < V_; ++v) {
            float mv = mk[v];
            const float* ar = acr + v*20;
            const float* nr = nar + v*20;
            float4 a0 = *(const float4*)(ar);
            float4 a1 = *(const float4*)(ar + 4);
            float4 a2 = *(const float4*)(ar + 8);
            float4 a3 = *(const float4*)(ar + 12);
            float  a4 = ar[16];
            float4 q0 = *(const float4*)(nr);
            float4 q1 = *(const float4*)(nr + 4);
            float4 q2 = *(const float4*)(nr + 8);
            float4 q3 = *(const float4*)(nr + 12);
            float  q4 = nr[16];
            yv[0]  += mv*(a0.x+q0.x); yv[1]  += mv*(a0.y+q0.y);
            yv[2]  += mv*(a0.z+q0.z); yv[3]  += mv*(a0.w+q0.w);
            yv[4]  += mv*(a1.x+q1.x); yv[5]  += mv*(a1.y+q1.y);
            yv[6]  += mv*(a1.z+q1.z); yv[7]  += mv*(a1.w+q1.w);
            yv[8]  += mv*(a2.x+q2.x); yv[9]  += mv*(a2.y+q2.y);
            yv[10] += mv*(a2.z+q2.z); yv[11] += mv*(a2.w+q2.w);
            yv[12] += mv*(a3.x+q3.x); yv[13] += mv*(a3.y+q3.y);
            yv[14] += mv*(a3.z+q3.z); yv[15] += mv*(a3.w+q3.w);
            yv[16] += mv*(a4+q4);
        }
    }

    float sw = 0.f;
#pragma unroll
    for (int w = 0; w < V_; ++w) sw += yv[w];
    atomicAdd(&pool_s[c], sw);

    // ---- stage y through LDS (reuse xs), then coalesced float4 writes ----
    __syncthreads();   // everyone done reading xs (conv) before overwrite
    float* ys = xs;
#pragma unroll
    for (int w = 0; w < V_; ++w) ys[c*68 + t*17 + w] = yv[w];
    __syncthreads();

    float* yg = y + (size_t)n * (COUT*TV) + (size_t)t0 * V_;
    for (int i = tid; i < 64*17; i += 256) {
        int cc = i / 17, q = i % 17;
        float4 val = *(const float4*)&ys[cc*68 + q*4];
        *(float4*)(yg + (size_t)cc*TV + q*4) = val;
    }
    if (tid < COUT) atomicAdd(&pooled[n*COUT + tid], pool_s[tid]);
}

// ---------------- K4: channel conv1d + sigmoid ------------------------
__global__ void k4_sig(const float* __restrict__ pooled, const float* __restrict__ cha_w,
                       float* __restrict__ sig) {
    int idx = threadIdx.x + blockIdx.x * 256;
    if (idx >= NCH) return;
    int c = idx & 63;
    const float inv = 1.f / (float)TV;
    float pm = pooled[idx] * inv;
    float pl = (c > 0)  ? pooled[idx - 1] * inv : 0.f;
    float pr = (c < 63) ? pooled[idx + 1] * inv : 0.f;
    float cr = cha_w[0]*pl + cha_w[1]*pm + cha_w[2]*pr;
    sig[idx] = 1.f / (1.f + expf(-cr));
}

// ---------------- K5: gate + BN + residual + relu (in place) ----------
__global__ __launch_bounds__(256) void k5_final(
    const float* __restrict__ x0, const float* __restrict__ sig,
    const float* __restrict__ gamma, const float* __restrict__ beta,
    float* __restrict__ y) {
    const float inv_sqrt = rsqrtf(1.f + 1e-5f);
    long long i = (long long)blockIdx.x * 256 + threadIdx.x;
    const long long total = (long long)N_*COUT*TV/4;  // 8,912,896
    const long long stride = (long long)gridDim.x * 256;
    for (; i < total; i += stride) {
        int nc = (int)(i / (TV/4));    // 1088 float4 per (n,c)
        int c = nc & 63;
        float a = (1.f + sig[nc]) * gamma[c] * inv_sqrt;
        float b = beta[c];
        float4 yv = ((const float4*)y)[i];
        float4 xv = ((const float4*)x0)[i];
        float4 o;
        o.x = fmaxf(yv.x*a + b + xv.x, 0.f);
        o.y = fmaxf(yv.y*a + b + xv.y, 0.f);
        o.z = fmaxf(yv.z*a + b + xv.z, 0.f);
        o.w = fmaxf(yv.w*a + b + xv.w, 0.f);
        ((float4*)y)[i] = o;
    }
}

extern "C" void kernel_launch(void* const* d_in, const int* in_sizes, int n_in,
                              void* d_out, int out_size, void* d_ws, size_t ws_size,
                              hipStream_t stream) {
    const float* x0     = (const float*)d_in[0];
    const float* conv_w = (const float*)d_in[1];
    const float* conv_b = (const float*)d_in[2];
    const float* spa_w  = (const float*)d_in[3];
    const float* spa_b  = (const float*)d_in[4];
    const float* mix_w  = (const float*)d_in[5];
    const float* mix_b  = (const float*)d_in[6];
    const float* A_GEME = (const float*)d_in[7];
    const float* A_SE   = (const float*)d_in[8];
    const float* cha_w  = (const float*)d_in[9];
    const float* gamma  = (const float*)d_in[10];
    const float* beta   = (const float*)d_in[11];

    float* ws    = (float*)d_ws;
    float* xbar  = ws + OFF_XBAR;
    float* wbar  = ws + OFF_WBAR;
    float* bbar  = ws + OFF_BBAR;
    float* pooled= ws + OFF_POOL;
    float* sig   = ws + OFF_SIG;
    float* ac05  = ws + OFF_AC;
    float* na    = ws + OFF_NA;
    float* y     = (float*)d_out;

    hipMemsetAsync(pooled, 0, NCH*sizeof(float), stream);
    k1_xbar<<<NCH, 272, 0, stream>>>(x0, xbar);
    k2a_wbar<<<28, 256, 0, stream>>>(conv_w, conv_b, A_SE, A_GEME, wbar, bbar, na);
    k2_attn<<<N_, 256, 0, stream>>>(xbar, wbar, bbar, spa_w, spa_b,
                                    mix_w, mix_b, ac05);
    k3_main<<<dim3(64, 128), 256, 0, stream>>>(x0, conv_w, conv_b, ac05, na, y, pooled);
    k4_sig<<<32, 256, 0, stream>>>(pooled, cha_w, sig);
    k5_final<<<2048, 256, 0, stream>>>(x0, sig, gamma, beta, y);
}

// Round 3
// 238.270 us; speedup vs baseline: 26.9854x; 2.0777x over previous
//
#include <hip/hip_runtime.h>
#include <math.h>

typedef __bf16 bf16;
typedef __attribute__((ext_vector_type(8))) __bf16 bf16x8;
typedef __attribute__((ext_vector_type(4))) __bf16 bf16x4;
typedef __attribute__((ext_vector_type(4))) float f32x4;

#define N_    128
#define CIN   64
#define COUT  64
#define T_    256
#define V_    17
#define K_    3
#define NCH   (N_*COUT)        // 8192
#define TV    (T_*V_)          // 4352

// workspace layout (float offsets)
#define OFF_XBAR  0
#define SZ_XBAR   (NCH*V_)                 // 139264
#define OFF_WBAR  (OFF_XBAR+SZ_XBAR)       // 139264
#define SZ_WBAR   1536
#define OFF_BBAR  (OFF_WBAR+SZ_WBAR)       // 140800
#define SZ_BBAR   32
#define OFF_RSA   (OFF_BBAR+SZ_BBAR)       // 140832  rsA[n][12][17]
#define SZ_RSA    (N_*12*V_)               // 26112
#define OFF_RSNA  (OFF_RSA+SZ_RSA)         // 166944  rsNA[24][17]
#define SZ_RSNA   408
#define OFF_A     (OFF_RSNA+SZ_RSNA)       // 167352  a[n][c]
#define SZ_A      NCH                      // 8192
#define OFF_WFRAG (OFF_A+SZ_A)             // 175544 (16B aligned) — 12288 bf16
#define SZ_WFRAG  6144
#define OFF_AFB   (OFF_WFRAG+SZ_WFRAG)     // 181688 (16B aligned) — 12.58M bf16
#define SZ_AFB    (N_*98304/2)             // 6291456 floats

// ---------------- K1: xbar[n,c,v] = mean_t x0[n,c,t,v] ----------------
__global__ __launch_bounds__(272) void k1_xbar(const float* __restrict__ x0,
                                               float* __restrict__ xbar) {
    int nc = blockIdx.x;
    __shared__ float s[272];
    const float* p = x0 + (size_t)nc * TV;
    int tid = threadIdx.x;
    float acc = 0.f;
#pragma unroll
    for (int j = 0; j < 16; ++j) acc += p[j*272 + tid];
    s[tid] = acc;
    __syncthreads();
    if (tid < V_) {
        float t = 0.f;
#pragma unroll
        for (int ts = 0; ts < 16; ++ts) t += s[ts*V_ + tid];
        xbar[nc*V_ + tid] = t * (1.f / (float)T_);
    }
}

// ------- K2a: wbar/bbar (attn), rsNA, W fragments (bf16, MFMA order) --
__global__ void k2a(const float* __restrict__ cw, const float* __restrict__ cb,
                    const float* __restrict__ A_SE, const float* __restrict__ A_GEME,
                    float* __restrict__ wbar, float* __restrict__ bbar,
                    float* __restrict__ rsna, bf16* __restrict__ wfrag) {
    int idx = threadIdx.x + blockIdx.x * 256;
    if (idx < 1536) {
        int o4 = idx >> 6, c = idx & 63;
        int k = o4 >> 3, jq = o4 & 7;
        int j = jq >> 1, q = jq & 1;
        int ob = k*64 + j*16 + q*8;
        float s = 0.f;
#pragma unroll
        for (int c8 = 0; c8 < 8; ++c8) s += cw[(ob + c8)*64 + c];
        wbar[idx] = s * 0.125f;
    }
    if (idx < 24) {
        int k = idx >> 3, jq = idx & 7;
        int j = jq >> 1, q = jq & 1;
        int ob = k*64 + j*16 + q*8;
        float s = 0.f;
#pragma unroll
        for (int c8 = 0; c8 < 8; ++c8) s += cb[ob + c8];
        bbar[idx] = s * 0.125f;
    }
    if (idx < 408) {  // rsNA[k*8+g][v] = sum_w (A_SE+A_GEME)
        int kg = idx / V_, v = idx % V_;
        float s = 0.f;
#pragma unroll
        for (int w = 0; w < V_; ++w)
            s += A_SE[kg*289 + v*17 + w] + A_GEME[kg*289 + v*17 + w];
        rsna[idx] = s;
    }
    if (idx < 12288) {  // wfrag[ot][s][lane][j] = conv_w[ot*16+(l&15)][s*32+(l>>4)*8+j]
        int j = idx & 7, l = (idx >> 3) & 63, s = (idx >> 9) & 1, ot = idx >> 10;
        int o  = ot*16 + (l & 15);
        int ci = s*32 + ((l >> 4)*8) + j;
        wfrag[idx] = (bf16)cw[o*64 + ci];
    }
}

// -------- K2: attention math -> AfB fragments (bf16) + rsA ------------
__global__ __launch_bounds__(256) void k2_attn(
    const float* __restrict__ xbar, const float* __restrict__ wbar,
    const float* __restrict__ bbar,
    const float* __restrict__ spa_w, const float* __restrict__ spa_b,
    const float* __restrict__ mix_w, const float* __restrict__ mix_b,
    const float* __restrict__ A_SE, const float* __restrict__ A_GEME,
    unsigned* __restrict__ afb_u, float* __restrict__ rsA) {
    int n = blockIdx.x;
    int tid = threadIdx.x;
    __shared__ float xb[CIN*V_];
    __shared__ float wb[24*64];
    __shared__ float bb[24];
    __shared__ float sw_[289], sb_[17], mw_[289], mb_[17];
    __shared__ float QK[24*V_];
    __shared__ float F[4*12*V_];
    __shared__ float S_[12*V_*V_];
    __shared__ float X_[9*V_*V_];
    __shared__ float AC[12*V_*V_];   // atten chunks m1..m4 per k

    for (int i = tid; i < CIN*V_; i += 256) xb[i] = xbar[n*CIN*V_ + i];
    for (int i = tid; i < 24*64; i += 256) wb[i] = wbar[i];
    if (tid < 24) bb[tid] = bbar[tid];
    for (int i = tid; i < 289; i += 256) { sw_[i] = spa_w[i]; mw_[i] = mix_w[i]; }
    if (tid < 17) { sb_[tid] = spa_b[tid]; mb_[tid] = mix_b[tid]; }
    __syncthreads();

    for (int i = tid; i < 24*V_; i += 256) {
        int o4 = i / V_, v = i % V_;
        float s = bb[o4];
        for (int c = 0; c < CIN; ++c) s += xb[c*V_ + v] * wb[o4*64 + c];
        QK[i] = s;
    }
    __syncthreads();

    for (int i = tid; i < 4*12*V_; i += 256) {
        int f = i / (12*V_); int r = i % (12*V_);
        int u = r / V_; int vp = r % V_;
        int k = u >> 2, j = u & 3;
        int q = (f == 1 || f == 2) ? 1 : 0;
        const float* src  = &QK[(k*8 + j*2 + q) * V_];
        const float* wmat = (f <= 1) ? sw_ : mw_;
        const float* bvec = (f <= 1) ? sb_ : mb_;
        float s = bvec[vp];
#pragma unroll
        for (int v = 0; v < V_; ++v) s += src[v] * wmat[vp*V_ + v];
        F[i] = fmaxf(s, 0.f);
    }
    __syncthreads();

    for (int r = tid; r < (12+9)*V_; r += 256) {
        float a; const float* brow; float* orow;
        if (r < 12*V_) {
            int u = r / V_, v = r % V_;
            a = F[0*12*V_ + u*V_ + v];
            brow = &F[1*12*V_ + u*V_];
            orow = &S_[u*V_*V_ + v*V_];
        } else {
            int rx = r - 12*V_;
            int xu = rx / V_, v = rx % V_;
            int k = xu / 3, j = xu % 3;
            a = F[2*12*V_ + (k*4 + j)*V_ + v];
            brow = &F[3*12*V_ + (k*4 + j + 1)*V_];
            orow = &X_[xu*V_*V_ + v*V_];
        }
        float vals[V_];
        float mx = -1e30f;
#pragma unroll
        for (int w = 0; w < V_; ++w) { vals[w] = a * brow[w]; mx = fmaxf(mx, vals[w]); }
        float sum = 0.f;
#pragma unroll
        for (int w = 0; w < V_; ++w) { vals[w] = expf(vals[w] - mx); sum += vals[w]; }
        float inv = 1.f / sum;
#pragma unroll
        for (int w = 0; w < V_; ++w) orow[w] = vals[w] * inv;
    }
    __syncthreads();

    for (int i = tid; i < 12*V_*V_; i += 256) {
        int u = i / (V_*V_); int vw = i % (V_*V_);
        int k = u >> 2, jj = u & 3;
        int xb3 = k*3;
        float s = 0.5f * S_[i];
        if (jj == 0)      s += 0.25f *  X_[(xb3+0)*V_*V_ + vw];
        else if (jj == 1) s += 0.25f * (X_[(xb3+0)*V_*V_ + vw] + X_[(xb3+1)*V_*V_ + vw]);
        else if (jj == 2) s += 0.25f * (X_[(xb3+1)*V_*V_ + vw] + X_[(xb3+2)*V_*V_ + vw]);
        else              s += 0.25f *  X_[(xb3+2)*V_*V_ + vw];
        AC[i] = s;   // atten chunk value
    }
    __syncthreads();

    // AfB fragments: [k][jb][g][nt][lane][j-pair] as u32 (2 bf16)
    // element (v,w): v = (lane>>4)*8 + jp*2 + jj, w = nt*16 + (lane&15)
    // Af = 0.5*AC[k][jb] + (A_SE+A_GEME)[k][g]; 0 outside 17x17
    unsigned* outu = afb_u + (size_t)n * 49152;
    for (int i = tid; i < 49152; i += 256) {
        int jp = i & 3, lane = (i >> 2) & 63, nt = (i >> 8) & 1;
        int g = (i >> 9) & 7, jb = (i >> 12) & 3, k = i >> 14;
        int w = nt*16 + (lane & 15);
        unsigned short us[2];
#pragma unroll
        for (int jj = 0; jj < 2; ++jj) {
            int v = (lane >> 4)*8 + jp*2 + jj;
            float val = 0.f;
            if (v < 17 && w < 17) {
                val = 0.5f * AC[(k*4 + jb)*289 + v*17 + w]
                    + A_SE[(k*8 + g)*289 + v*17 + w]
                    + A_GEME[(k*8 + g)*289 + v*17 + w];
            }
            bf16 b = (bf16)val;
            __builtin_memcpy(&us[jj], &b, 2);
        }
        outu[i] = (unsigned)us[0] | ((unsigned)us[1] << 16);
    }
    // rsA[n][u][v] = sum_w 0.5*AC[u][v][w]
    for (int i = tid; i < 12*V_; i += 256) {
        int u = i / V_, v = i % V_;
        float s = 0.f;
#pragma unroll
        for (int w = 0; w < V_; ++w) s += AC[u*289 + v*17 + w];
        rsA[n*204 + i] = 0.5f * s;
    }
}

// -------- K_SIG: analytic pooled -> sigmoid gate -> a[n][c] -----------
__global__ __launch_bounds__(64) void k_sig(
    const float* __restrict__ xbar, const float* __restrict__ cw,
    const float* __restrict__ cb, const float* __restrict__ rsA,
    const float* __restrict__ rsna, const float* __restrict__ cha_w,
    const float* __restrict__ gamma, float* __restrict__ a_out) {
    int n = blockIdx.x, c = threadIdx.x;
    __shared__ float xb[CIN*V_];
    __shared__ float ps[COUT];
    for (int i = c; i < CIN*V_; i += 64) xb[i] = xbar[n*CIN*V_ + i];
    __syncthreads();
    int jb = c >> 4, g = c & 7;
    float pool = 0.f;
#pragma unroll
    for (int k = 0; k < 3; ++k) {
        float mb[V_];
        float b = cb[k*64 + c];
#pragma unroll
        for (int v = 0; v < V_; ++v) mb[v] = b;
        for (int ci = 0; ci < CIN; ++ci) {
            float w = cw[(k*64 + c)*64 + ci];
#pragma unroll
            for (int v = 0; v < V_; ++v) mb[v] += w * xb[ci*V_ + v];
        }
        const float* rA = rsA + n*204 + (k*4 + jb)*V_;
        const float* rN = rsna + (k*8 + g)*V_;
#pragma unroll
        for (int v = 0; v < V_; ++v) pool += mb[v] * (rA[v] + rN[v]);
    }
    ps[c] = pool * (1.f / 17.f);
    __syncthreads();
    float pm = ps[c];
    float pl = (c > 0)  ? ps[c-1] : 0.f;
    float pr = (c < 63) ? ps[c+1] : 0.f;
    float cr = cha_w[0]*pl + cha_w[1]*pm + cha_w[2]*pr;
    float sig = 1.f / (1.f + expf(-cr));
    a_out[n*64 + c] = (1.f + sig) * gamma[c] * rsqrtf(1.f + 1e-5f);
}

// -------- K3: MFMA conv + apply + fused epilogue ----------------------
// block: (n, t0 tile of 8). 256 threads = 4 waves. Wave w owns channels c=w*16..w*16+15.
// LDS: Xs (X^T[tvp=160][ci=64] bf16, 20480B, swz ^((tvp&7)<<4))
//      Ms (m[c=64][t=8][v=32] bf16, 32768B, swz ^(((t^(c&3))&7)<<4))
__global__ __launch_bounds__(256, 3) void k3_main(
    const float* __restrict__ x0, const float* __restrict__ cb,
    const bf16* __restrict__ wfrag, const bf16* __restrict__ afb,
    const float* __restrict__ a_g, const float* __restrict__ beta,
    float* __restrict__ out) {
    int bid = blockIdx.x;
    int orig = (bid & 7)*512 + (bid >> 3);      // XCD-chunked swizzle (4096%8==0)
    int n = orig >> 5;
    int t0 = (orig & 31) * 8;
    int tid = threadIdx.x, lane = tid & 63, wave = tid >> 6;

    __shared__ __align__(16) unsigned char smem[53248];
    unsigned char* Xs = smem;
    unsigned char* Ms = smem + 20480;

    // zero Xs pad rows (v=17..19 for each t): b32 writes
    for (int i = tid; i < 24*32; i += 256) {
        int row = i >> 5, ci2 = i & 31;
        int t = row / 3, e = row % 3;
        int tvp = t*20 + 17 + e;
        *(unsigned*)(Xs + ((tvp*128 + ci2*4) ^ ((tvp & 7) << 4))) = 0u;
    }
    // zero Ms v=20..31: 3x b64 per (c,t)
    for (int i = tid; i < 64*8*3; i += 256) {
        int c = i / 24; int r = i % 24; int t = r / 3; int part = r % 3;
        int off = (c*512 + t*64 + 40 + part*8) ^ (((t ^ (c & 3)) & 7) << 4);
        *(unsigned long long*)(Ms + off) = 0ull;
    }
    // stage Xs: x0[n, ci, t0..t0+7, v] -> bf16 X^T[t*20+v][ci]
    const float* xsrc = x0 + (size_t)n * (CIN*TV) + (size_t)t0 * V_;
    for (int i = tid; i < 2176; i += 256) {
        int ci = i / 34, r4 = i % 34;
        f32x4 xv = *(const f32x4*)(xsrc + (size_t)ci*TV + r4*4);
#pragma unroll
        for (int u = 0; u < 4; ++u) {
            int r = r4*4 + u;           // 0..135
            int t = r / 17, v = r % 17;
            int tvp = t*20 + v;
            *(bf16*)(Xs + ((tvp*128 + ci*2) ^ ((tvp & 7) << 4))) = (bf16)xv[u];
        }
    }
    __syncthreads();

    f32x4 acc[8][2] = {};
    int cbw = wave * 16;
    int l15 = lane & 15, lg = lane >> 4;

#pragma unroll
    for (int k = 0; k < 3; ++k) {
        // ---- conv: this wave computes o-tile (k*4+wave) = channels cbw..cbw+15 ----
        const bf16* wfp = wfrag + (size_t)((k*4 + wave)*2) * 512;
        bf16x8 wf0 = *(const bf16x8*)(wfp + lane*8);
        bf16x8 wf1 = *(const bf16x8*)(wfp + 512 + lane*8);
        int cconv = cbw + l15;
        float bias = cb[k*64 + cconv];
        int cswz_w = cconv & 3;
#pragma unroll
        for (int mt = 0; mt < 10; ++mt) {
            int tvp = mt*16 + l15;
            int arow = tvp*128, sw = (tvp & 7) << 4;
            bf16x8 a0 = *(const bf16x8*)(Xs + ((arow + lg*16) ^ sw));
            bf16x8 a1 = *(const bf16x8*)(Xs + ((arow + 64 + lg*16) ^ sw));
            f32x4 d = {0.f, 0.f, 0.f, 0.f};
            d = __builtin_amdgcn_mfma_f32_16x16x32_bf16(a0, wf0, d, 0, 0, 0);
            d = __builtin_amdgcn_mfma_f32_16x16x32_bf16(a1, wf1, d, 0, 0, 0);
            int tvpd = mt*16 + lg*4;
            int td = tvpd / 20, vg = (tvpd % 20) >> 2;
            bf16x4 mv;
            mv[0] = (bf16)(d[0] + bias);
            mv[1] = (bf16)(d[1] + bias);
            mv[2] = (bf16)(d[2] + bias);
            mv[3] = (bf16)(d[3] + bias);
            int mo = (cconv*512 + td*64 + vg*8) ^ (((td ^ cswz_w) & 7) << 4);
            *(bf16x4*)(Ms + mo) = mv;
        }
        __syncthreads();

        // ---- apply: y[(c,t)][w] += m[c][t][v] * Af[v][w] ----
        const bf16* afbn = afb + (size_t)n * 98304;
        int r = l15;
        int ta = r & 7;
#pragma unroll
        for (int p = 0; p < 8; ++p) {
            int ca = cbw + p + 8*(r >> 3);
            bf16x8 am = *(const bf16x8*)(Ms +
                ((ca*512 + ta*64 + lg*16) ^ (((ta ^ (ca & 3)) & 7) << 4)));
            size_t afoff = (size_t)(((k*4 + wave)*8 + p)) * 1024 + lane*8;
            bf16x8 b0 = *(const bf16x8*)(afbn + afoff);
            bf16x8 b1 = *(const bf16x8*)(afbn + afoff + 512);
            acc[p][0] = __builtin_amdgcn_mfma_f32_16x16x32_bf16(am, b0, acc[p][0], 0, 0, 0);
            acc[p][1] = __builtin_amdgcn_mfma_f32_16x16x32_bf16(am, b1, acc[p][1], 0, 0, 0);
        }
        __syncthreads();
    }

    // ---- epilogue: out = relu(x0 + a*y + beta), coalesced 64B sectors ----
    const float* a_row = a_g + n*64;
    float* outn = out + (size_t)n * (COUT*TV);
    const float* x0n = x0 + (size_t)n * (COUT*TV);
    int chi = lg >> 1;
    int tb = (lg & 1) * 4;
#pragma unroll
    for (int p = 0; p < 8; ++p) {
        int c = cbw + p + 8*chi;
        float ac = a_row[c];
        float bc = beta[c];
        size_t base = (size_t)c*TV + (size_t)(t0 + tb)*V_;
#pragma unroll
        for (int i = 0; i < 4; ++i) {
            size_t idx = base + i*V_ + l15;
            outn[idx] = fmaxf(x0n[idx] + ac*acc[p][0][i] + bc, 0.f);
        }
        if (l15 == 0) {
#pragma unroll
            for (int i = 0; i < 4; ++i) {
                size_t idx = base + i*V_ + 16;
                outn[idx] = fmaxf(x0n[idx] + ac*acc[p][1][i] + bc, 0.f);
            }
        }
    }
}

extern "C" void kernel_launch(void* const* d_in, const int* in_sizes, int n_in,
                              void* d_out, int out_size, void* d_ws, size_t ws_size,
                              hipStream_t stream) {
    const float* x0     = (const float*)d_in[0];
    const float* conv_w = (const float*)d_in[1];
    const float* conv_b = (const float*)d_in[2];
    const float* spa_w  = (const float*)d_in[3];
    const float* spa_b  = (const float*)d_in[4];
    const float* mix_w  = (const float*)d_in[5];
    const float* mix_b  = (const float*)d_in[6];
    const float* A_GEME = (const float*)d_in[7];
    const float* A_SE   = (const float*)d_in[8];
    const float* cha_w  = (const float*)d_in[9];
    const float* gamma  = (const float*)d_in[10];
    const float* beta   = (const float*)d_in[11];

    float* ws    = (float*)d_ws;
    float* xbar  = ws + OFF_XBAR;
    float* wbar  = ws + OFF_WBAR;
    float* bbar  = ws + OFF_BBAR;
    float* rsA   = ws + OFF_RSA;
    float* rsna  = ws + OFF_RSNA;
    float* a_g   = ws + OFF_A;
    bf16*  wfrag = (bf16*)(ws + OFF_WFRAG);
    bf16*  afb   = (bf16*)(ws + OFF_AFB);
    float* y     = (float*)d_out;

    k1_xbar<<<NCH, 272, 0, stream>>>(x0, xbar);
    k2a<<<48, 256, 0, stream>>>(conv_w, conv_b, A_SE, A_GEME, wbar, bbar, rsna, wfrag);
    k2_attn<<<N_, 256, 0, stream>>>(xbar, wbar, bbar, spa_w, spa_b,
                                    mix_w, mix_b, A_SE, A_GEME,
                                    (unsigned*)afb, rsA);
    k_sig<<<N_, 64, 0, stream>>>(xbar, conv_w, conv_b, rsA, rsna, cha_w, gamma, a_g);
    k3_main<<<4096, 256, 0, stream>>>(x0, conv_b, wfrag, afb, a_g, beta, y);
}

// Round 4
// 183.305 us; speedup vs baseline: 35.0771x; 1.2999x over previous
//
#include <hip/hip_runtime.h>
#include <math.h>

typedef __bf16 bf16;
typedef __attribute__((ext_vector_type(8))) __bf16 bf16x8;
typedef __attribute__((ext_vector_type(4))) __bf16 bf16x4;
typedef __attribute__((ext_vector_type(4))) float f32x4;

#define N_    128
#define CIN   64
#define COUT  64
#define T_    256
#define V_    17
#define K_    3
#define NCH   (N_*COUT)        // 8192
#define TV    (T_*V_)          // 4352

// workspace layout (float offsets; all 16B-aligned)
#define OFF_XBAR  0
#define SZ_XBAR   (NCH*V_)                 // 139264
#define OFF_A     (OFF_XBAR+SZ_XBAR)       // 139264  a[n][c]
#define SZ_A      NCH                      // 8192
#define OFF_WFRAG (OFF_A+SZ_A)             // 147456  12288 bf16
#define SZ_WFRAG  6144
#define OFF_AFB   (OFF_WFRAG+SZ_WFRAG)     // 153600  12.58M bf16
#define SZ_AFB    (N_*98304/2)             // 6291456 floats

// ---------------- K1: xbar[n,c,v] = mean_t x0[n,c,t,v] ----------------
// 272 threads, float4: elem (4*(tid+272j)+u) mod 17 == (4tid+u) mod 17 (1088%17==0)
__global__ __launch_bounds__(272) void k1_xbar(const float* __restrict__ x0,
                                               float* __restrict__ xbar) {
    int nc = blockIdx.x;
    __shared__ float s[1088];
    const f32x4* p = (const f32x4*)(x0 + (size_t)nc * TV);
    int tid = threadIdx.x;
    float a0 = 0.f, a1 = 0.f, a2 = 0.f, a3 = 0.f;
#pragma unroll
    for (int j = 0; j < 4; ++j) {
        f32x4 v = p[tid + 272*j];
        a0 += v[0]; a1 += v[1]; a2 += v[2]; a3 += v[3];
    }
    s[4*tid+0] = a0; s[4*tid+1] = a1; s[4*tid+2] = a2; s[4*tid+3] = a3;
    __syncthreads();
    if (tid < V_) {
        float t = 0.f;
#pragma unroll
        for (int m = 0; m < 64; ++m) t += s[tid + 17*m];
        xbar[nc*V_ + tid] = t * (1.f / (float)T_);
    }
}

// -------- K2F: wbar/bbar local + attention -> afb + wfrag + a_g -------
// grid 256: block = (n = bid>>1, half = bid&1)
__global__ __launch_bounds__(256) void k2f(
    const float* __restrict__ xbar, const float* __restrict__ cw,
    const float* __restrict__ cb,
    const float* __restrict__ spa_w, const float* __restrict__ spa_b,
    const float* __restrict__ mix_w, const float* __restrict__ mix_b,
    const float* __restrict__ A_SE, const float* __restrict__ A_GEME,
    const float* __restrict__ cha_w, const float* __restrict__ gamma,
    unsigned* __restrict__ afb_u, bf16* __restrict__ wfrag,
    float* __restrict__ a_out) {
    int bid = blockIdx.x;
    int n = bid >> 1, half = bid & 1;
    int tid = threadIdx.x;
    __shared__ float xb[CIN*V_];     // [ci][v]
    __shared__ float wb[24*64];
    __shared__ float bb[24];
    __shared__ float sw_[289], sb_[17], mw_[289], mb_[17];
    __shared__ float na_s[24*289];   // A_SE+A_GEME
    __shared__ float rsna[24*V_];
    __shared__ float QK[24*V_];
    __shared__ float F[4*12*V_];
    __shared__ float S_[12*289];
    __shared__ float X_[9*289];
    __shared__ float AC[12*289];
    __shared__ float rsac[12*V_];
    __shared__ float psk[192];
    __shared__ float ps[64];

    for (int i = tid; i < CIN*V_; i += 256) xb[i] = xbar[n*CIN*V_ + i];
    for (int i = tid; i < 24*64; i += 256) {
        int o4 = i >> 6, c = i & 63;
        int k = o4 >> 3, jq = o4 & 7;
        int ob = k*64 + (jq >> 1)*16 + (jq & 1)*8;
        float s = 0.f;
#pragma unroll
        for (int c8 = 0; c8 < 8; ++c8) s += cw[(ob + c8)*64 + c];
        wb[i] = s * 0.125f;
    }
    if (tid < 24) {
        int k = tid >> 3, jq = tid & 7;
        int ob = k*64 + (jq >> 1)*16 + (jq & 1)*8;
        float s = 0.f;
#pragma unroll
        for (int c8 = 0; c8 < 8; ++c8) s += cb[ob + c8];
        bb[tid] = s * 0.125f;
    }
    for (int i = tid; i < 289; i += 256) { sw_[i] = spa_w[i]; mw_[i] = mix_w[i]; }
    if (tid < 17) { sb_[tid] = spa_b[tid]; mb_[tid] = mix_b[tid]; }
    for (int i = tid; i < 24*289; i += 256) na_s[i] = A_SE[i] + A_GEME[i];
    __syncthreads();

    for (int i = tid; i < 24*V_; i += 256) {   // rsna
        int kg = i / V_, v = i % V_;
        float s = 0.f;
#pragma unroll
        for (int w = 0; w < V_; ++w) s += na_s[kg*289 + v*17 + w];
        rsna[i] = s;
    }
    for (int i = tid; i < 24*V_; i += 256) {   // QK
        int o4 = i / V_, v = i % V_;
        float s = bb[o4];
        for (int c = 0; c < CIN; ++c) s += xb[c*V_ + v] * wb[o4*64 + c];
        QK[i] = s;
    }
    __syncthreads();

    for (int i = tid; i < 4*12*V_; i += 256) {
        int f = i / (12*V_); int r = i % (12*V_);
        int u = r / V_; int vp = r % V_;
        int k = u >> 2, j = u & 3;
        int q = (f == 1 || f == 2) ? 1 : 0;
        const float* src  = &QK[(k*8 + j*2 + q) * V_];
        const float* wmat = (f <= 1) ? sw_ : mw_;
        const float* bvec = (f <= 1) ? sb_ : mb_;
        float s = bvec[vp];
#pragma unroll
        for (int v = 0; v < V_; ++v) s += src[v] * wmat[vp*V_ + v];
        F[i] = fmaxf(s, 0.f);
    }
    __syncthreads();

    for (int r = tid; r < (12+9)*V_; r += 256) {
        float a; const float* brow; float* orow;
        if (r < 12*V_) {
            int u = r / V_, v = r % V_;
            a = F[0*12*V_ + u*V_ + v];
            brow = &F[1*12*V_ + u*V_];
            orow = &S_[u*289 + v*V_];
        } else {
            int rx = r - 12*V_;
            int xu = rx / V_, v = rx % V_;
            int k = xu / 3, j = xu % 3;
            a = F[2*12*V_ + (k*4 + j)*V_ + v];
            brow = &F[3*12*V_ + (k*4 + j + 1)*V_];
            orow = &X_[xu*289 + v*V_];
        }
        float vals[V_];
        float mx = -1e30f;
#pragma unroll
        for (int w = 0; w < V_; ++w) { vals[w] = a * brow[w]; mx = fmaxf(mx, vals[w]); }
        float sum = 0.f;
#pragma unroll
        for (int w = 0; w < V_; ++w) { vals[w] = expf(vals[w] - mx); sum += vals[w]; }
        float inv = 1.f / sum;
#pragma unroll
        for (int w = 0; w < V_; ++w) orow[w] = vals[w] * inv;
    }
    __syncthreads();

    for (int i = tid; i < 12*289; i += 256) {
        int u = i / 289; int vw = i % 289;
        int k = u >> 2, jj = u & 3;
        int xb3 = k*3;
        float s = 0.5f * S_[i];
        if (jj == 0)      s += 0.25f *  X_[(xb3+0)*289 + vw];
        else if (jj == 1) s += 0.25f * (X_[(xb3+0)*289 + vw] + X_[(xb3+1)*289 + vw]);
        else if (jj == 2) s += 0.25f * (X_[(xb3+1)*289 + vw] + X_[(xb3+2)*289 + vw]);
        else              s += 0.25f *  X_[(xb3+2)*289 + vw];
        AC[i] = s;
    }
    __syncthreads();

    for (int i = tid; i < 12*V_; i += 256) {    // rsac = 0.5*rowsum(AC)
        int u = i / V_, v = i % V_;
        float s = 0.f;
#pragma unroll
        for (int w = 0; w < V_; ++w) s += AC[u*289 + v*17 + w];
        rsac[i] = 0.5f * s;
    }
    __syncthreads();

    // afb half-write: [k][jb][g][nt][lane][jp] u32
    unsigned* outu = afb_u + (size_t)n * 49152;
    for (int i = tid + half*24576; i < 24576 + half*24576; i += 256) {
        int jp = i & 3, lane = (i >> 2) & 63, nt = (i >> 8) & 1;
        int g = (i >> 9) & 7, jb = (i >> 12) & 3, k = i >> 14;
        int w = nt*16 + (lane & 15);
        unsigned short us[2];
#pragma unroll
        for (int jj = 0; jj < 2; ++jj) {
            int v = (lane >> 4)*8 + jp*2 + jj;
            float val = 0.f;
            if (v < 17 && w < 17) {
                val = 0.5f * AC[(k*4 + jb)*289 + v*17 + w]
                    + na_s[(k*8 + g)*289 + v*17 + w];
            }
            bf16 b = (bf16)val;
            __builtin_memcpy(&us[jj], &b, 2);
        }
        outu[i] = (unsigned)us[0] | ((unsigned)us[1] << 16);
    }
    // wfrag (half 1 blocks; duplicate identical writes are benign)
    if (half) {
        for (int i = tid; i < 12288; i += 256) {
            int j = i & 7, l = (i >> 3) & 63, s = (i >> 9) & 1, ot = i >> 10;
            int o  = ot*16 + (l & 15);
            int ci = s*32 + ((l >> 4)*8) + j;
            wfrag[i] = (bf16)cw[o*64 + ci];
        }
    }
    // analytic pooled -> sigmoid -> a_g (half 0)
    if (half == 0 && tid < 192) {
        int k = tid >> 6, c = tid & 63;
        float mb[V_];
        float b = cb[k*64 + c];
#pragma unroll
        for (int v = 0; v < V_; ++v) mb[v] = b;
        for (int ci = 0; ci < CIN; ++ci) {
            float w = cw[(k*64 + c)*64 + ci];
#pragma unroll
            for (int v = 0; v < V_; ++v) mb[v] += w * xb[ci*V_ + v];
        }
        int jb = c >> 4, g = c & 7;
        float pool = 0.f;
#pragma unroll
        for (int v = 0; v < V_; ++v)
            pool += mb[v] * (rsac[(k*4 + jb)*V_ + v] + rsna[(k*8 + g)*V_ + v]);
        psk[tid] = pool;
    }
    __syncthreads();
    if (half == 0 && tid < 64) {
        ps[tid] = (psk[tid] + psk[64 + tid] + psk[128 + tid]) * (1.f / 17.f);
    }
    __syncthreads();
    if (half == 0 && tid < 64) {
        int c = tid;
        float pm = ps[c];
        float pl = (c > 0)  ? ps[c-1] : 0.f;
        float pr = (c < 63) ? ps[c+1] : 0.f;
        float cr = cha_w[0]*pl + cha_w[1]*pm + cha_w[2]*pr;
        float sig = 1.f / (1.f + expf(-cr));
        a_out[n*64 + c] = (1.f + sig) * gamma[c] * rsqrtf(1.f + 1e-5f);
    }
}

// -------- K3: MFMA conv + apply + fused epilogue ----------------------
// block: (n, t0 tile of 8). 256 threads = 4 waves. Wave w owns channels c=w*16..w*16+15.
// LDS: Xs (X^T[tvp=160][ci=64] bf16, 20480B, swz ^((tvp&7)<<4))
//      Ms (m[c=64][t=8][v=32] bf16, 32768B, swz ^(((t^(c&3))&7)<<4))
__global__ __launch_bounds__(256, 3) void k3_main(
    const float* __restrict__ x0, const float* __restrict__ cb,
    const bf16* __restrict__ wfrag, const bf16* __restrict__ afb,
    const float* __restrict__ a_g, const float* __restrict__ beta,
    float* __restrict__ out) {
    int bid = blockIdx.x;
    int orig = (bid & 7)*512 + (bid >> 3);      // XCD-chunked swizzle (4096%8==0)
    int n = orig >> 5;
    int t0 = (orig & 31) * 8;
    int tid = threadIdx.x, lane = tid & 63, wave = tid >> 6;

    __shared__ __align__(16) unsigned char smem[53248];
    unsigned char* Xs = smem;
    unsigned char* Ms = smem + 20480;

    // zero Ms v=20..31: 3x b64 per (c,t)
    for (int i = tid; i < 64*8*3; i += 256) {
        int c = i / 24; int r = i % 24; int t = r / 3; int part = r % 3;
        int off = (c*512 + t*64 + 40 + part*8) ^ (((t ^ (c & 3)) & 7) << 4);
        *(unsigned long long*)(Ms + off) = 0ull;
    }
    // stage Xs: transpose on the global-read side; one b64 LDS write per iter.
    // thread handles (tvp, ci4): 4 coalesced dword streams at TV stride.
    const float* xsrc = x0 + (size_t)n * (CIN*TV) + (size_t)t0 * V_;
    for (int i = tid; i < 2560; i += 256) {
        int tvp = i % 160;          // consecutive lanes -> consecutive tvp
        int ci4 = i / 160;
        int t = tvp / 20, v = tvp % 20;
        bf16x4 bv = {(bf16)0.f, (bf16)0.f, (bf16)0.f, (bf16)0.f};
        if (v < 17) {
            const float* p = xsrc + (size_t)(ci4*4)*TV + t*V_ + v;
            bv[0] = (bf16)p[0];
            bv[1] = (bf16)p[TV];
            bv[2] = (bf16)p[2*TV];
            bv[3] = (bf16)p[3*TV];
        }
        *(bf16x4*)(Xs + ((tvp*128 + ci4*8) ^ ((tvp & 7) << 4))) = bv;
    }
    __syncthreads();

    f32x4 acc[8][2] = {};
    int cbw = wave * 16;
    int l15 = lane & 15, lg = lane >> 4;

#pragma unroll
    for (int k = 0; k < 3; ++k) {
        // ---- conv: this wave computes o-tile (k*4+wave) = channels cbw..cbw+15 ----
        const bf16* wfp = wfrag + (size_t)((k*4 + wave)*2) * 512;
        bf16x8 wf0 = *(const bf16x8*)(wfp + lane*8);
        bf16x8 wf1 = *(const bf16x8*)(wfp + 512 + lane*8);
        int cconv = cbw + l15;
        float bias = cb[k*64 + cconv];
        int cswz_w = cconv & 3;
#pragma unroll
        for (int mt = 0; mt < 10; ++mt) {
            int tvp = mt*16 + l15;
            int arow = tvp*128, sw = (tvp & 7) << 4;
            bf16x8 a0 = *(const bf16x8*)(Xs + ((arow + lg*16) ^ sw));
            bf16x8 a1 = *(const bf16x8*)(Xs + ((arow + 64 + lg*16) ^ sw));
            f32x4 d = {0.f, 0.f, 0.f, 0.f};
            d = __builtin_amdgcn_mfma_f32_16x16x32_bf16(a0, wf0, d, 0, 0, 0);
            d = __builtin_amdgcn_mfma_f32_16x16x32_bf16(a1, wf1, d, 0, 0, 0);
            int tvpd = mt*16 + lg*4;
            int td = tvpd / 20, vg = (tvpd % 20) >> 2;
            bf16x4 mv;
            mv[0] = (bf16)(d[0] + bias);
            mv[1] = (bf16)(d[1] + bias);
            mv[2] = (bf16)(d[2] + bias);
            mv[3] = (bf16)(d[3] + bias);
            int mo = (cconv*512 + td*64 + vg*8) ^ (((td ^ cswz_w) & 7) << 4);
            *(bf16x4*)(Ms + mo) = mv;
        }
        __syncthreads();

        // ---- apply: y[(c,t)][w] += m[c][t][v] * Af[v][w] ----
        const bf16* afbn = afb + (size_t)n * 98304;
        int r = l15;
        int ta = r & 7;
#pragma unroll
        for (int p = 0; p < 8; ++p) {
            int ca = cbw + p + 8*(r >> 3);
            bf16x8 am = *(const bf16x8*)(Ms +
                ((ca*512 + ta*64 + lg*16) ^ (((ta ^ (ca & 3)) & 7) << 4)));
            size_t afoff = (size_t)(((k*4 + wave)*8 + p)) * 1024 + lane*8;
            bf16x8 b0 = *(const bf16x8*)(afbn + afoff);
            bf16x8 b1 = *(const bf16x8*)(afbn + afoff + 512);
            acc[p][0] = __builtin_amdgcn_mfma_f32_16x16x32_bf16(am, b0, acc[p][0], 0, 0, 0);
            acc[p][1] = __builtin_amdgcn_mfma_f32_16x16x32_bf16(am, b1, acc[p][1], 0, 0, 0);
        }
        __syncthreads();
    }

    // ---- epilogue: out = relu(x0 + a*y + beta), coalesced 64B sectors ----
    const float* a_row = a_g + n*64;
    float* outn = out + (size_t)n * (COUT*TV);
    const float* x0n = x0 + (size_t)n * (COUT*TV);
    int chi = lg >> 1;
    int tb = (lg & 1) * 4;
#pragma unroll
    for (int p = 0; p < 8; ++p) {
        int c = cbw + p + 8*chi;
        float ac = a_row[c];
        float bc = beta[c];
        size_t base = (size_t)c*TV + (size_t)(t0 + tb)*V_;
#pragma unroll
        for (int i = 0; i < 4; ++i) {
            size_t idx = base + i*V_ + l15;
            outn[idx] = fmaxf(x0n[idx] + ac*acc[p][0][i] + bc, 0.f);
        }
        if (l15 == 0) {
#pragma unroll
            for (int i = 0; i < 4; ++i) {
                size_t idx = base + i*V_ + 16;
                outn[idx] = fmaxf(x0n[idx] + ac*acc[p][1][i] + bc, 0.f);
            }
        }
    }
}

extern "C" void kernel_launch(void* const* d_in, const int* in_sizes, int n_in,
                              void* d_out, int out_size, void* d_ws, size_t ws_size,
                              hipStream_t stream) {
    const float* x0     = (const float*)d_in[0];
    const float* conv_w = (const float*)d_in[1];
    const float* conv_b = (const float*)d_in[2];
    const float* spa_w  = (const float*)d_in[3];
    const float* spa_b  = (const float*)d_in[4];
    const float* mix_w  = (const float*)d_in[5];
    const float* mix_b  = (const float*)d_in[6];
    const float* A_GEME = (const float*)d_in[7];
    const float* A_SE   = (const float*)d_in[8];
    const float* cha_w  = (const float*)d_in[9];
    const float* gamma  = (const float*)d_in[10];
    const float* beta   = (const float*)d_in[11];

    float* ws    = (float*)d_ws;
    float* xbar  = ws + OFF_XBAR;
    float* a_g   = ws + OFF_A;
    bf16*  wfrag = (bf16*)(ws + OFF_WFRAG);
    bf16*  afb   = (bf16*)(ws + OFF_AFB);
    float* y     = (float*)d_out;

    k1_xbar<<<NCH, 272, 0, stream>>>(x0, xbar);
    k2f<<<256, 256, 0, stream>>>(xbar, conv_w, conv_b, spa_w, spa_b,
                                 mix_w, mix_b, A_SE, A_GEME, cha_w, gamma,
                                 (unsigned*)afb, wfrag, a_g);
    k3_main<<<4096, 256, 0, stream>>>(x0, conv_b, wfrag, afb, a_g, beta, y);
}